// Round 19
// baseline (524.605 us; speedup 1.0000x reference)
//
#include <hip/hip_runtime.h>
#include <math.h>

#define NN 10000
#define NE 640000
#define H 128
#define H2 256
#define XD 8
#define ED 8
#define YD 112
#define NL 4
#define EPS_MSG 1e-7f
#define EPS_SM 1e-16f
#define EPS_LN 1e-5f
#define TMA 4
#define NBA (NN / TMA)   // 2500 (ea_mm1 blocks)
#define TM 8
#define NB1 (NN / TM)    // 1250 (mm2 blocks)
#define TNO 16
#define NBO (NN / TNO)   // 625 (mmout blocks)

typedef _Float16 h2 __attribute__((ext_vector_type(2)));

// ---------- CSR build ----------
__global__ void hist_k(const int* __restrict__ dst, int* __restrict__ counts) {
    int e = blockIdx.x * 256 + threadIdx.x;
    if (e < NE) atomicAdd(&counts[dst[e]], 1);
}

__global__ void scan_k(const int* __restrict__ counts, int* __restrict__ rowptr) {
    __shared__ int part[1024];
    int tid = threadIdx.x;
    const int CH = (NN + 1023) / 1024;  // 10
    int base = tid * CH;
    int s = 0;
    for (int j = 0; j < CH; j++) { int i = base + j; if (i < NN) s += counts[i]; }
    part[tid] = s; __syncthreads();
    for (int off = 1; off < 1024; off <<= 1) {
        int v = (tid >= off) ? part[tid - off] : 0;
        __syncthreads();
        part[tid] += v;
        __syncthreads();
    }
    int run = part[tid] - s;  // exclusive prefix
    for (int j = 0; j < CH; j++) {
        int i = base + j;
        if (i < NN) { rowptr[i] = run; run += counts[i]; }
    }
    if (tid == 1023) rowptr[NN] = run;  // == NE
}

// edge CSR scatter: perm[pos] = e  (random 4B writes, 2.5 MB target)
__global__ void scatter_k(const int* __restrict__ dst, const int* __restrict__ rowptr,
                          int* __restrict__ fill, int* __restrict__ perm) {
    int e = blockIdx.x * 256 + threadIdx.x;   // NE = 2500*256 exact
    int d = dst[e];
    int pos = rowptr[d] + atomicAdd(&fill[d], 1);
    perm[pos] = e;
}

// pack + node encoder fused (also writes fp16 shadow of h)
__global__ void __launch_bounds__(256) packenc_k(
    const int* __restrict__ perm, const int* __restrict__ src,
    const float* __restrict__ eattr, int* __restrict__ srcs,
    _Float16* __restrict__ eacsr,
    const float* __restrict__ x, const float* __restrict__ Wn,
    const float* __restrict__ bn, float* __restrict__ h,
    _Float16* __restrict__ rh16) {
    int b = blockIdx.x;
    if (b < 2500) {                      // ---- pack (NE = 2500*256 exact) ----
        int pos = b * 256 + threadIdx.x;
        int e = perm[pos];
        srcs[pos] = src[e];
        const float4* ein = (const float4*)eattr;
        float4 a = ein[(size_t)e * 2];
        float4 bb = ein[(size_t)e * 2 + 1];
        float4 pk;
        _Float16* pp = (_Float16*)&pk;
        pp[0] = (_Float16)a.x; pp[1] = (_Float16)a.y; pp[2] = (_Float16)a.z; pp[3] = (_Float16)a.w;
        pp[4] = (_Float16)bb.x; pp[5] = (_Float16)bb.y; pp[6] = (_Float16)bb.z; pp[7] = (_Float16)bb.w;
        ((float4*)eacsr)[pos] = pk;      // coalesced 16 B store
    } else {                             // ---- node enc: 2 nodes/block ----
        int bb = b - 2500;               // 0..4999
        int c = threadIdx.x & 127, ln = threadIdx.x >> 7;
        int n = bb * 2 + ln;
        const float4* xr = (const float4*)(x + (size_t)n * XD);
        float4 x0 = xr[0], x1 = xr[1];
        float acc = bn[c];
        acc = fmaf(x0.x, Wn[0 * H + c], acc); acc = fmaf(x0.y, Wn[1 * H + c], acc);
        acc = fmaf(x0.z, Wn[2 * H + c], acc); acc = fmaf(x0.w, Wn[3 * H + c], acc);
        acc = fmaf(x1.x, Wn[4 * H + c], acc); acc = fmaf(x1.y, Wn[5 * H + c], acc);
        acc = fmaf(x1.z, Wn[6 * H + c], acc); acc = fmaf(x1.w, Wn[7 * H + c], acc);
        h[(size_t)n * H + c] = acc;
        rh16[(size_t)n * H + c] = (_Float16)acc;
    }
}

// ---------- fused: edge agg (4 nodes, 2 waves each, parity-split) -> LDS -> mm1 ----------
__global__ void __launch_bounds__(512) ea_mm1_k(
    const float* __restrict__ rin, const _Float16* __restrict__ rh16,
    const int* __restrict__ rowptr,
    const int* __restrict__ srcs, const _Float16* __restrict__ eacsr,
    const float* __restrict__ We, const float* __restrict__ be,
    const float* __restrict__ tptr, int layer,
    const float* __restrict__ W1i, const float* __restrict__ b1i,
    float* __restrict__ y1, float* __restrict__ part) {
    int nb = blockIdx.x, tid = threadIdx.x;
    int n0 = nb * TMA;
    __shared__ float denp[2][TMA][H];  // 4 KB
    __shared__ float nump[2][TMA][H];  // 4 KB
    __shared__ float a[TMA][H];        // 2 KB

    // ---- edge phase: wave wv -> node (wv>>1), parity (wv&1); lane owns ch 2l,2l+1 ----
    {
        int wv = tid >> 6, l = tid & 63;
        int nd = wv >> 1, p = wv & 1;
        int c0 = 2 * l;
        int n = n0 + nd;
        h2 wA[4], wB[4];
#pragma unroll
        for (int k = 0; k < 4; k++) {
            wA[k][0] = (_Float16)We[(2 * k) * H + c0];
            wA[k][1] = (_Float16)We[(2 * k + 1) * H + c0];
            wB[k][0] = (_Float16)We[(2 * k) * H + c0 + 1];
            wB[k][1] = (_Float16)We[(2 * k + 1) * H + c0 + 1];
        }
        float becA = be[c0], becB = be[c0 + 1];
        float ts2 = tptr[layer] * 1.44269504088896f;  // t * log2(e)
        int beg = __builtin_amdgcn_readfirstlane(rowptr[n]);
        int end = __builtin_amdgcn_readfirstlane(rowptr[n + 1]);
        float denA = 0.f, numA = 0.f, denB = 0.f, numB = 0.f;
#pragma unroll 4
        for (int j = beg + p; j < end; j += 2) {
            int sn = srcs[j];                                       // uniform -> scalar
            float4 raw = *(const float4*)(eacsr + (size_t)j * ED);  // uniform -> scalar
            const h2* ep = (const h2*)&raw;
            h2 hv2 = *(const h2*)(rh16 + (size_t)sn * H + c0);      // 4 B/lane gather
            float hvA = (float)hv2[0], hvB = (float)hv2[1];
            float pA = __builtin_amdgcn_fdot2(ep[0], wA[0], becA, false);
            pA = __builtin_amdgcn_fdot2(ep[1], wA[1], pA, false);
            pA = __builtin_amdgcn_fdot2(ep[2], wA[2], pA, false);
            pA = __builtin_amdgcn_fdot2(ep[3], wA[3], pA, false);
            float pB = __builtin_amdgcn_fdot2(ep[0], wB[0], becB, false);
            pB = __builtin_amdgcn_fdot2(ep[1], wB[1], pB, false);
            pB = __builtin_amdgcn_fdot2(ep[2], wB[2], pB, false);
            pB = __builtin_amdgcn_fdot2(ep[3], wB[3], pB, false);
            float msgA = fmaxf(hvA + pA, 0.f) + EPS_MSG;
            float msgB = fmaxf(hvB + pB, 0.f) + EPS_MSG;
            float peA = __builtin_amdgcn_exp2f(msgA * ts2);
            float peB = __builtin_amdgcn_exp2f(msgB * ts2);
            denA += peA; numA = fmaf(peA, msgA, numA);
            denB += peB; numB = fmaf(peB, msgB, numB);
        }
        denp[p][nd][c0] = denA; denp[p][nd][c0 + 1] = denB;
        nump[p][nd][c0] = numA; nump[p][nd][c0 + 1] = numB;
    }
    __syncthreads();
    // ---- combine (fixed order: parity0 + parity1) ----
    {
        int nd = tid >> 7, c = tid & 127;   // 4 nodes x 128 channels = 512
        float den = denp[0][nd][c] + denp[1][nd][c];
        float num = nump[0][nd][c] + nump[1][nd][c];
        a[nd][c] = num / (den + EPS_SM) + rin[(size_t)(n0 + nd) * H + c];
    }
    __syncthreads();

    // ---- mm1 phase: o = tid&255 output channel; half = tid>>8 owns 2 rows ----
    int o = tid & 255, half = tid >> 8;
    int rb = half * 2;
    float acc[2] = {0.f, 0.f};
    for (int k = 0; k < H; k += 4) {
        float w0 = W1i[k * H2 + o];
        float w1 = W1i[(k + 1) * H2 + o];
        float w2 = W1i[(k + 2) * H2 + o];
        float w3 = W1i[(k + 3) * H2 + o];
#pragma unroll
        for (int i = 0; i < 2; i++) {
            float4 av = *(const float4*)&a[rb + i][k];  // ds_read_b128 broadcast
            acc[i] = fmaf(av.x, w0, acc[i]);
            acc[i] = fmaf(av.y, w1, acc[i]);
            acc[i] = fmaf(av.z, w2, acc[i]);
            acc[i] = fmaf(av.w, w3, acc[i]);
        }
    }
    float bo = b1i[o];
    float ps = 0.f, ps2 = 0.f;
#pragma unroll
    for (int i = 0; i < 2; i++) {
        float v = acc[i] + bo;
        y1[(size_t)(n0 + rb + i) * H2 + o] = v;
        ps += v; ps2 += v * v;
    }
#pragma unroll
    for (int off = 32; off; off >>= 1) { ps += __shfl_xor(ps, off); ps2 += __shfl_xor(ps2, off); }
    __shared__ float red[16];
    int w8 = tid >> 6;
    if ((tid & 63) == 0) { red[w8] = ps; red[8 + w8] = ps2; }
    __syncthreads();
    if (tid == 0) {
        float S = 0.f, S2 = 0.f;
#pragma unroll
        for (int i = 0; i < 8; i++) { S += red[i]; S2 += red[8 + i]; }
        part[nb * 2] = S;
        part[nb * 2 + 1] = S2;
    }
}

// ---------- z = relu(graph_ln(y1)); h (+)= z @ W2[i] + b2[i]; r = relu(node_ln(h)) ----------
// Row-split: 256 threads; half = tid>>7 owns 4 of the block's 8 rows; o = tid&127.
__global__ void __launch_bounds__(256) mm2_k(const float* __restrict__ y1,
    const float* __restrict__ g1i, const float* __restrict__ bt1i,
    const float* __restrict__ W2i, const float* __restrict__ b2i,
    const float* __restrict__ part, float* __restrict__ h,
    const float* __restrict__ lgp, const float* __restrict__ lbp,
    float* __restrict__ r, _Float16* __restrict__ rh16, int first) {
    int nb = blockIdx.x, tid = threadIdx.x;
    int o = tid & 127, half = tid >> 7;
    int rb = half * 4;             // this half's first local row
    int n0 = nb * TM;
    // ---- graph-LN stats from partials (identical fixed order in every block) ----
    float s = 0.f, s2 = 0.f;
    for (int i = tid; i < NBA; i += 256) { s += part[2 * i]; s2 += part[2 * i + 1]; }
#pragma unroll
    for (int off = 32; off; off >>= 1) { s += __shfl_xor(s, off); s2 += __shfl_xor(s2, off); }
    __shared__ float sred[8];
    int w4 = tid >> 6;
    if ((tid & 63) == 0) { sred[w4] = s; sred[4 + w4] = s2; }
    __syncthreads();
    const float M = (float)NN * (float)H2;
    float m = (sred[0] + sred[1] + sred[2] + sred[3]) / M;
    float var = fmaxf((sred[4] + sred[5] + sred[6] + sred[7]) / M - m * m, 0.f);
    float istd = 1.f / (sqrtf(var) + EPS_LN);

    __shared__ float z[TM][H2];  // 8 KB
    __syncthreads();
    {
        const float4* y4 = (const float4*)(y1 + (size_t)n0 * H2);
        const float4* g4 = (const float4*)g1i;
        const float4* b4 = (const float4*)bt1i;
        float4* z4 = (float4*)z;
#pragma unroll
        for (int t = tid; t < TM * H2 / 4; t += 256) {  // 512 float4s, 2/thread
            int k4 = t & 63;
            float4 v = y4[t];
            float4 g = g4[k4], b = b4[k4];
            v.x = fmaxf((v.x - m) * istd * g.x + b.x, 0.f);
            v.y = fmaxf((v.y - m) * istd * g.y + b.y, 0.f);
            v.z = fmaxf((v.z - m) * istd * g.z + b.z, 0.f);
            v.w = fmaxf((v.w - m) * istd * g.w + b.w, 0.f);
            z4[t] = v;
        }
    }
    __syncthreads();
    float acc[4];
#pragma unroll
    for (int i = 0; i < 4; i++) acc[i] = 0.f;
    for (int k = 0; k < H2; k += 4) {
        float w0 = W2i[k * H + o];
        float w1 = W2i[(k + 1) * H + o];
        float w2 = W2i[(k + 2) * H + o];
        float w3 = W2i[(k + 3) * H + o];
#pragma unroll
        for (int i = 0; i < 4; i++) {
            float4 zv = *(const float4*)&z[rb + i][k];  // ds_read_b128 broadcast
            acc[i] = fmaf(zv.x, w0, acc[i]);
            acc[i] = fmaf(zv.y, w1, acc[i]);
            acc[i] = fmaf(zv.z, w2, acc[i]);
            acc[i] = fmaf(zv.w, w3, acc[i]);
        }
    }
    float bo = b2i[o];
    float vv[4];
#pragma unroll
    for (int i = 0; i < 4; i++) {
        size_t idx = (size_t)(n0 + rb + i) * H + o;
        float v = acc[i] + bo;
        if (!first) v += h[idx];
        h[idx] = v;
        vv[i] = v;
    }
    // fused node-LN + ReLU -> r (fp32) + rh16 (fp16 shadow for next layer's gather)
    __shared__ float rs[2][2][4], rs2[2][2][4];
    int w2i_ = (tid >> 6) & 1;     // wave within half
#pragma unroll
    for (int i = 0; i < 4; i++) {
        float ss = vv[i], ss2 = vv[i] * vv[i];
#pragma unroll
        for (int off = 32; off; off >>= 1) { ss += __shfl_xor(ss, off); ss2 += __shfl_xor(ss2, off); }
        if ((tid & 63) == 0) { rs[half][w2i_][i] = ss; rs2[half][w2i_][i] = ss2; }
    }
    __syncthreads();
    float gc = lgp[o], bc = lbp[o];
#pragma unroll
    for (int i = 0; i < 4; i++) {
        float S = rs[half][0][i] + rs[half][1][i];
        float S2 = rs2[half][0][i] + rs2[half][1][i];
        float mn = S * (1.f / H);
        float vr = S2 * (1.f / H) - mn * mn;
        float inv = rsqrtf(vr + EPS_LN);
        float ov = fmaxf((vv[i] - mn) * inv * gc + bc, 0.f);
        size_t idx = (size_t)(n0 + rb + i) * H + o;
        r[idx] = ov;
        rh16[idx] = (_Float16)ov;
    }
}

// ---------- out = r @ Wout + bout ----------
__global__ void __launch_bounds__(128) mmout_k(const float* __restrict__ r,
    const float* __restrict__ Wout, const float* __restrict__ bout,
    float* __restrict__ out) {
    int nb = blockIdx.x, o = threadIdx.x;
    int n0 = nb * TNO;
    __shared__ float a[TNO][H];
    {
        const float4* r4 = (const float4*)(r + (size_t)n0 * H);
        float4* a4 = (float4*)a;
        for (int t = o; t < TNO * H / 4; t += 128) a4[t] = r4[t];
    }
    __syncthreads();
    if (o < YD) {
        float acc[TNO];
#pragma unroll
        for (int i = 0; i < TNO; i++) acc[i] = 0.f;
        for (int k = 0; k < H; k += 4) {
            float w0 = Wout[k * YD + o];
            float w1 = Wout[(k + 1) * YD + o];
            float w2 = Wout[(k + 2) * YD + o];
            float w3 = Wout[(k + 3) * YD + o];
#pragma unroll
            for (int i = 0; i < TNO; i++) {
                float4 av = *(const float4*)&a[i][k];
                acc[i] = fmaf(av.x, w0, acc[i]);
                acc[i] = fmaf(av.y, w1, acc[i]);
                acc[i] = fmaf(av.z, w2, acc[i]);
                acc[i] = fmaf(av.w, w3, acc[i]);
            }
        }
        float bo = bout[o];
#pragma unroll
        for (int i = 0; i < TNO; i++) out[(size_t)(n0 + i) * YD + o] = acc[i] + bo;
    }
}

extern "C" void kernel_launch(void* const* d_in, const int* in_sizes, int n_in,
                              void* d_out, int out_size, void* d_ws, size_t ws_size,
                              hipStream_t stream) {
    const float* x    = (const float*)d_in[0];
    const int*   ei   = (const int*)d_in[1];
    const float* eattr= (const float*)d_in[2];
    const float* Wn   = (const float*)d_in[3];
    const float* bn   = (const float*)d_in[4];
    const float* We   = (const float*)d_in[5];
    const float* be   = (const float*)d_in[6];
    const float* t    = (const float*)d_in[7];
    const float* W1   = (const float*)d_in[8];
    const float* b1   = (const float*)d_in[9];
    const float* g1   = (const float*)d_in[10];
    const float* bt1  = (const float*)d_in[11];
    const float* W2   = (const float*)d_in[12];
    const float* b2   = (const float*)d_in[13];
    const float* lng  = (const float*)d_in[14];
    const float* lnb  = (const float*)d_in[15];
    const float* Wout = (const float*)d_in[16];
    const float* bout = (const float*)d_in[17];
    float* out = (float*)d_out;

    const int* src = ei;        // edge_index[0]
    const int* dst = ei + NE;   // edge_index[1]

    char* ws = (char*)d_ws;
    size_t off = 0;
    auto alloc = [&](size_t bytes) -> char* {
        char* p = ws + off;
        off += (bytes + 255) & ~(size_t)255;
        return p;
    };
    int*      counts = (int*)alloc((size_t)NN * 2 * 4);  // counts | fill contiguous
    int*      fill   = counts + NN;
    int*      rowptr = (int*)alloc((size_t)(NN + 1) * 4);
    int*      perm   = (int*)alloc((size_t)NE * 4);
    int*      srcs   = (int*)alloc((size_t)NE * 4);
    _Float16* eacsr  = (_Float16*)alloc((size_t)NE * ED * 2);  // 10 MB fp16
    float*    h      = (float*)alloc((size_t)NN * H * 4);
    float*    r      = (float*)alloc((size_t)NN * H * 4);
    _Float16* rh16   = (_Float16*)alloc((size_t)NN * H * 2);   // fp16 gather shadow
    float*    y1     = (float*)alloc((size_t)NN * H2 * 4);
    float*    part   = (float*)alloc((size_t)NBA * 2 * 4);
    (void)ws_size; (void)in_sizes; (void)n_in; (void)out_size;

    hipMemsetAsync(counts, 0, (size_t)NN * 2 * 4, stream);

    hist_k<<<(NE + 255) / 256, 256, 0, stream>>>(dst, counts);
    scan_k<<<1, 1024, 0, stream>>>(counts, rowptr);
    scatter_k<<<NE / 256, 256, 0, stream>>>(dst, rowptr, fill, perm);
    packenc_k<<<2500 + NN / 2, 256, 0, stream>>>(perm, src, eattr, srcs, eacsr,
                                                 x, Wn, bn, h, rh16);

    for (int i = 0; i < NL; i++) {
        const float* cin = (i == 0) ? h : r;
        ea_mm1_k<<<NBA, 512, 0, stream>>>(cin, rh16, rowptr, srcs, eacsr,
                                          We, be, t, i,
                                          W1 + (size_t)i * H * H2, b1 + i * H2, y1, part);
        int nx = (i == NL - 1) ? 0 : (i + 1);  // next node-LN params (final uses layer 0's)
        mm2_k<<<NB1, 256, 0, stream>>>(y1, g1 + i * H2, bt1 + i * H2,
                                       W2 + (size_t)i * H2 * H, b2 + i * H, part, h,
                                       lng + nx * H, lnb + nx * H, r, rh16, (i == 0) ? 1 : 0);
    }
    mmout_k<<<NBO, 128, 0, stream>>>(r, Wout, bout, out);
}

// Round 20
// 471.251 us; speedup vs baseline: 1.1132x; 1.1132x over previous
//
#include <hip/hip_runtime.h>
#include <math.h>

#define NN 10000
#define NE 640000
#define H 128
#define H2 256
#define XD 8
#define ED 8
#define YD 112
#define NL 4
#define EPS_MSG 1e-7f
#define EPS_SM 1e-16f
#define EPS_LN 1e-5f
#define TM 8
#define NB1 (NN / TM)    // 1250 (ea_mm1/mm2 blocks)
#define TNO 16
#define NBO (NN / TNO)   // 625 (mmout blocks)

typedef _Float16 h2 __attribute__((ext_vector_type(2)));

// ---------- CSR build ----------
__global__ void hist_k(const int* __restrict__ dst, int* __restrict__ counts) {
    int e = blockIdx.x * 256 + threadIdx.x;
    if (e < NE) atomicAdd(&counts[dst[e]], 1);
}

__global__ void scan_k(const int* __restrict__ counts, int* __restrict__ rowptr) {
    __shared__ int part[1024];
    int tid = threadIdx.x;
    const int CH = (NN + 1023) / 1024;  // 10
    int base = tid * CH;
    int s = 0;
    for (int j = 0; j < CH; j++) { int i = base + j; if (i < NN) s += counts[i]; }
    part[tid] = s; __syncthreads();
    for (int off = 1; off < 1024; off <<= 1) {
        int v = (tid >= off) ? part[tid - off] : 0;
        __syncthreads();
        part[tid] += v;
        __syncthreads();
    }
    int run = part[tid] - s;  // exclusive prefix
    for (int j = 0; j < CH; j++) {
        int i = base + j;
        if (i < NN) { rowptr[i] = run; run += counts[i]; }
    }
    if (tid == 1023) rowptr[NN] = run;  // == NE
}

// pass 1: perm[pos] = e  (random 4B writes into 2.5 MB, L2-resident)
__global__ void scatter_k(const int* __restrict__ dst, const int* __restrict__ rowptr,
                          int* __restrict__ fill, int* __restrict__ perm) {
    int e = blockIdx.x * 256 + threadIdx.x;
    if (e >= NE) return;
    int d = dst[e];
    int pos = rowptr[d] + atomicAdd(&fill[d], 1);
    perm[pos] = e;
}

// pack + node encoder fused (also writes fp16 shadow of h)
__global__ void __launch_bounds__(256) packenc_k(
    const int* __restrict__ perm, const int* __restrict__ src,
    const float* __restrict__ eattr, int* __restrict__ srcs,
    _Float16* __restrict__ eacsr,
    const float* __restrict__ x, const float* __restrict__ Wn,
    const float* __restrict__ bn, float* __restrict__ h,
    _Float16* __restrict__ rh16) {
    int b = blockIdx.x;
    if (b < 2500) {                      // ---- pack (NE = 2500*256 exact) ----
        int pos = b * 256 + threadIdx.x;
        int e = perm[pos];
        srcs[pos] = src[e];
        const float4* ein = (const float4*)eattr;
        float4 a = ein[(size_t)e * 2];
        float4 bb = ein[(size_t)e * 2 + 1];
        float4 pk;
        _Float16* pp = (_Float16*)&pk;
        pp[0] = (_Float16)a.x; pp[1] = (_Float16)a.y; pp[2] = (_Float16)a.z; pp[3] = (_Float16)a.w;
        pp[4] = (_Float16)bb.x; pp[5] = (_Float16)bb.y; pp[6] = (_Float16)bb.z; pp[7] = (_Float16)bb.w;
        ((float4*)eacsr)[pos] = pk;      // coalesced 16 B store
    } else {                             // ---- node enc: 2 nodes/block ----
        int bb = b - 2500;               // 0..4999
        int c = threadIdx.x & 127, ln = threadIdx.x >> 7;
        int n = bb * 2 + ln;
        const float4* xr = (const float4*)(x + (size_t)n * XD);
        float4 x0 = xr[0], x1 = xr[1];
        float acc = bn[c];
        acc = fmaf(x0.x, Wn[0 * H + c], acc); acc = fmaf(x0.y, Wn[1 * H + c], acc);
        acc = fmaf(x0.z, Wn[2 * H + c], acc); acc = fmaf(x0.w, Wn[3 * H + c], acc);
        acc = fmaf(x1.x, Wn[4 * H + c], acc); acc = fmaf(x1.y, Wn[5 * H + c], acc);
        acc = fmaf(x1.z, Wn[6 * H + c], acc); acc = fmaf(x1.w, Wn[7 * H + c], acc);
        h[(size_t)n * H + c] = acc;
        rh16[(size_t)n * H + c] = (_Float16)acc;
    }
}

// ---------- fused: edge aggregation (8 nodes, 1 wave each; fp16 gather) -> LDS -> mm1 ----------
__global__ void __launch_bounds__(512) ea_mm1_k(
    const float* __restrict__ rin, const _Float16* __restrict__ rh16,
    const int* __restrict__ rowptr,
    const int* __restrict__ srcs, const _Float16* __restrict__ eacsr,
    const float* __restrict__ We, const float* __restrict__ be,
    const float* __restrict__ tptr, int layer,
    const float* __restrict__ W1i, const float* __restrict__ b1i,
    float* __restrict__ y1, float* __restrict__ part) {
    int nb = blockIdx.x, tid = threadIdx.x;
    int n0 = nb * TM;
    __shared__ float a[TM][H];  // 4 KB

    // ---- edge phase: wave wv owns node n0+wv; lane l owns adjacent channels 2l, 2l+1 ----
    {
        int wv = tid >> 6, l = tid & 63;
        int c0 = 2 * l;
        int n = n0 + wv;
        h2 wA[4], wB[4];
#pragma unroll
        for (int k = 0; k < 4; k++) {
            wA[k][0] = (_Float16)We[(2 * k) * H + c0];
            wA[k][1] = (_Float16)We[(2 * k + 1) * H + c0];
            wB[k][0] = (_Float16)We[(2 * k) * H + c0 + 1];
            wB[k][1] = (_Float16)We[(2 * k + 1) * H + c0 + 1];
        }
        float becA = be[c0], becB = be[c0 + 1];
        float ts2 = tptr[layer] * 1.44269504088896f;  // t * log2(e)
        int beg = __builtin_amdgcn_readfirstlane(rowptr[n]);
        int end = __builtin_amdgcn_readfirstlane(rowptr[n + 1]);
        const float2 rv = *(const float2*)(rin + (size_t)n * H + c0);  // fp32 residual
        float denA = 0.f, numA = 0.f, denB = 0.f, numB = 0.f;
#pragma unroll 4
        for (int j = beg; j < end; ++j) {
            int sn = srcs[j];                                       // uniform -> scalar
            float4 raw = *(const float4*)(eacsr + (size_t)j * ED);  // uniform -> scalar
            const h2* ep = (const h2*)&raw;
            h2 hv2 = *(const h2*)(rh16 + (size_t)sn * H + c0);      // 4 B/lane gather
            float hvA = (float)hv2[0], hvB = (float)hv2[1];
            float pA = __builtin_amdgcn_fdot2(ep[0], wA[0], becA, false);
            pA = __builtin_amdgcn_fdot2(ep[1], wA[1], pA, false);
            pA = __builtin_amdgcn_fdot2(ep[2], wA[2], pA, false);
            pA = __builtin_amdgcn_fdot2(ep[3], wA[3], pA, false);
            float pB = __builtin_amdgcn_fdot2(ep[0], wB[0], becB, false);
            pB = __builtin_amdgcn_fdot2(ep[1], wB[1], pB, false);
            pB = __builtin_amdgcn_fdot2(ep[2], wB[2], pB, false);
            pB = __builtin_amdgcn_fdot2(ep[3], wB[3], pB, false);
            float msgA = fmaxf(hvA + pA, 0.f) + EPS_MSG;
            float msgB = fmaxf(hvB + pB, 0.f) + EPS_MSG;
            float peA = __builtin_amdgcn_exp2f(msgA * ts2);
            float peB = __builtin_amdgcn_exp2f(msgB * ts2);
            denA += peA; numA = fmaf(peA, msgA, numA);
            denB += peB; numB = fmaf(peB, msgB, numB);
        }
        float2 av;
        av.x = numA / (denA + EPS_SM) + rv.x;
        av.y = numB / (denB + EPS_SM) + rv.y;
        *(float2*)&a[wv][c0] = av;
    }
    __syncthreads();

    // ---- mm1 phase: o = tid&255 output channel; half = tid>>8 owns 4 rows ----
    int o = tid & 255, half = tid >> 8;
    int rb = half * 4;
    float acc[4];
#pragma unroll
    for (int i = 0; i < 4; i++) acc[i] = 0.f;
    for (int k = 0; k < H; k += 4) {
        float w0 = W1i[k * H2 + o];
        float w1 = W1i[(k + 1) * H2 + o];
        float w2 = W1i[(k + 2) * H2 + o];
        float w3 = W1i[(k + 3) * H2 + o];
#pragma unroll
        for (int i = 0; i < 4; i++) {
            float4 av = *(const float4*)&a[rb + i][k];  // ds_read_b128 broadcast
            acc[i] = fmaf(av.x, w0, acc[i]);
            acc[i] = fmaf(av.y, w1, acc[i]);
            acc[i] = fmaf(av.z, w2, acc[i]);
            acc[i] = fmaf(av.w, w3, acc[i]);
        }
    }
    float bo = b1i[o];
    float ps = 0.f, ps2 = 0.f;
#pragma unroll
    for (int i = 0; i < 4; i++) {
        float v = acc[i] + bo;
        y1[(size_t)(n0 + rb + i) * H2 + o] = v;
        ps += v; ps2 += v * v;
    }
#pragma unroll
    for (int off = 32; off; off >>= 1) { ps += __shfl_xor(ps, off); ps2 += __shfl_xor(ps2, off); }
    __shared__ float red[16];
    int w8 = tid >> 6;
    if ((tid & 63) == 0) { red[w8] = ps; red[8 + w8] = ps2; }
    __syncthreads();
    if (tid == 0) {
        float S = 0.f, S2 = 0.f;
#pragma unroll
        for (int i = 0; i < 8; i++) { S += red[i]; S2 += red[8 + i]; }
        part[nb * 2] = S;
        part[nb * 2 + 1] = S2;
    }
}

// ---------- z = relu(graph_ln(y1)); h (+)= z @ W2[i] + b2[i]; r = relu(node_ln(h)) ----------
// Row-split: 256 threads; half = tid>>7 owns 4 of the block's 8 rows; o = tid&127.
__global__ void __launch_bounds__(256) mm2_k(const float* __restrict__ y1,
    const float* __restrict__ g1i, const float* __restrict__ bt1i,
    const float* __restrict__ W2i, const float* __restrict__ b2i,
    const float* __restrict__ part, float* __restrict__ h,
    const float* __restrict__ lgp, const float* __restrict__ lbp,
    float* __restrict__ r, _Float16* __restrict__ rh16, int first) {
    int nb = blockIdx.x, tid = threadIdx.x;
    int o = tid & 127, half = tid >> 7;
    int rb = half * 4;             // this half's first local row
    int n0 = nb * TM;
    // ---- graph-LN stats from partials (identical fixed order in every block) ----
    float s = 0.f, s2 = 0.f;
    for (int i = tid; i < NB1; i += 256) { s += part[2 * i]; s2 += part[2 * i + 1]; }
#pragma unroll
    for (int off = 32; off; off >>= 1) { s += __shfl_xor(s, off); s2 += __shfl_xor(s2, off); }
    __shared__ float sred[8];
    int w4 = tid >> 6;
    if ((tid & 63) == 0) { sred[w4] = s; sred[4 + w4] = s2; }
    __syncthreads();
    const float M = (float)NN * (float)H2;
    float m = (sred[0] + sred[1] + sred[2] + sred[3]) / M;
    float var = fmaxf((sred[4] + sred[5] + sred[6] + sred[7]) / M - m * m, 0.f);
    float istd = 1.f / (sqrtf(var) + EPS_LN);

    __shared__ float z[TM][H2];  // 8 KB
    __syncthreads();
    {
        const float4* y4 = (const float4*)(y1 + (size_t)n0 * H2);
        const float4* g4 = (const float4*)g1i;
        const float4* b4 = (const float4*)bt1i;
        float4* z4 = (float4*)z;
#pragma unroll
        for (int t = tid; t < TM * H2 / 4; t += 256) {  // 512 float4s, 2/thread
            int k4 = t & 63;
            float4 v = y4[t];
            float4 g = g4[k4], b = b4[k4];
            v.x = fmaxf((v.x - m) * istd * g.x + b.x, 0.f);
            v.y = fmaxf((v.y - m) * istd * g.y + b.y, 0.f);
            v.z = fmaxf((v.z - m) * istd * g.z + b.z, 0.f);
            v.w = fmaxf((v.w - m) * istd * g.w + b.w, 0.f);
            z4[t] = v;
        }
    }
    __syncthreads();
    float acc[4];
#pragma unroll
    for (int i = 0; i < 4; i++) acc[i] = 0.f;
    for (int k = 0; k < H2; k += 4) {
        float w0 = W2i[k * H + o];
        float w1 = W2i[(k + 1) * H + o];
        float w2 = W2i[(k + 2) * H + o];
        float w3 = W2i[(k + 3) * H + o];
#pragma unroll
        for (int i = 0; i < 4; i++) {
            float4 zv = *(const float4*)&z[rb + i][k];  // ds_read_b128 broadcast
            acc[i] = fmaf(zv.x, w0, acc[i]);
            acc[i] = fmaf(zv.y, w1, acc[i]);
            acc[i] = fmaf(zv.z, w2, acc[i]);
            acc[i] = fmaf(zv.w, w3, acc[i]);
        }
    }
    float bo = b2i[o];
    float vv[4];
#pragma unroll
    for (int i = 0; i < 4; i++) {
        size_t idx = (size_t)(n0 + rb + i) * H + o;
        float v = acc[i] + bo;
        if (!first) v += h[idx];
        h[idx] = v;
        vv[i] = v;
    }
    // fused node-LN + ReLU -> r (fp32) + rh16 (fp16 shadow for next layer's gather)
    __shared__ float rs[2][2][4], rs2[2][2][4];
    int w2i_ = (tid >> 6) & 1;     // wave within half
#pragma unroll
    for (int i = 0; i < 4; i++) {
        float ss = vv[i], ss2 = vv[i] * vv[i];
#pragma unroll
        for (int off = 32; off; off >>= 1) { ss += __shfl_xor(ss, off); ss2 += __shfl_xor(ss2, off); }
        if ((tid & 63) == 0) { rs[half][w2i_][i] = ss; rs2[half][w2i_][i] = ss2; }
    }
    __syncthreads();
    float gc = lgp[o], bc = lbp[o];
#pragma unroll
    for (int i = 0; i < 4; i++) {
        float S = rs[half][0][i] + rs[half][1][i];
        float S2 = rs2[half][0][i] + rs2[half][1][i];
        float mn = S * (1.f / H);
        float vr = S2 * (1.f / H) - mn * mn;
        float inv = rsqrtf(vr + EPS_LN);
        float ov = fmaxf((vv[i] - mn) * inv * gc + bc, 0.f);
        size_t idx = (size_t)(n0 + rb + i) * H + o;
        r[idx] = ov;
        rh16[idx] = (_Float16)ov;
    }
}

// ---------- out = r @ Wout + bout ----------
__global__ void __launch_bounds__(128) mmout_k(const float* __restrict__ r,
    const float* __restrict__ Wout, const float* __restrict__ bout,
    float* __restrict__ out) {
    int nb = blockIdx.x, o = threadIdx.x;
    int n0 = nb * TNO;
    __shared__ float a[TNO][H];
    {
        const float4* r4 = (const float4*)(r + (size_t)n0 * H);
        float4* a4 = (float4*)a;
        for (int t = o; t < TNO * H / 4; t += 128) a4[t] = r4[t];
    }
    __syncthreads();
    if (o < YD) {
        float acc[TNO];
#pragma unroll
        for (int i = 0; i < TNO; i++) acc[i] = 0.f;
        for (int k = 0; k < H; k += 4) {
            float w0 = Wout[k * YD + o];
            float w1 = Wout[(k + 1) * YD + o];
            float w2 = Wout[(k + 2) * YD + o];
            float w3 = Wout[(k + 3) * YD + o];
#pragma unroll
            for (int i = 0; i < TNO; i++) {
                float4 av = *(const float4*)&a[i][k];
                acc[i] = fmaf(av.x, w0, acc[i]);
                acc[i] = fmaf(av.y, w1, acc[i]);
                acc[i] = fmaf(av.z, w2, acc[i]);
                acc[i] = fmaf(av.w, w3, acc[i]);
            }
        }
        float bo = bout[o];
#pragma unroll
        for (int i = 0; i < TNO; i++) out[(size_t)(n0 + i) * YD + o] = acc[i] + bo;
    }
}

extern "C" void kernel_launch(void* const* d_in, const int* in_sizes, int n_in,
                              void* d_out, int out_size, void* d_ws, size_t ws_size,
                              hipStream_t stream) {
    const float* x    = (const float*)d_in[0];
    const int*   ei   = (const int*)d_in[1];
    const float* eattr= (const float*)d_in[2];
    const float* Wn   = (const float*)d_in[3];
    const float* bn   = (const float*)d_in[4];
    const float* We   = (const float*)d_in[5];
    const float* be   = (const float*)d_in[6];
    const float* t    = (const float*)d_in[7];
    const float* W1   = (const float*)d_in[8];
    const float* b1   = (const float*)d_in[9];
    const float* g1   = (const float*)d_in[10];
    const float* bt1  = (const float*)d_in[11];
    const float* W2   = (const float*)d_in[12];
    const float* b2   = (const float*)d_in[13];
    const float* lng  = (const float*)d_in[14];
    const float* lnb  = (const float*)d_in[15];
    const float* Wout = (const float*)d_in[16];
    const float* bout = (const float*)d_in[17];
    float* out = (float*)d_out;

    const int* src = ei;        // edge_index[0]
    const int* dst = ei + NE;   // edge_index[1]

    char* ws = (char*)d_ws;
    size_t off = 0;
    auto alloc = [&](size_t bytes) -> char* {
        char* p = ws + off;
        off += (bytes + 255) & ~(size_t)255;
        return p;
    };
    int*      counts = (int*)alloc((size_t)NN * 2 * 4);  // counts | fill contiguous
    int*      fill   = counts + NN;
    int*      rowptr = (int*)alloc((size_t)(NN + 1) * 4);
    int*      perm   = (int*)alloc((size_t)NE * 4);
    int*      srcs   = (int*)alloc((size_t)NE * 4);
    _Float16* eacsr  = (_Float16*)alloc((size_t)NE * ED * 2);  // 10 MB fp16
    float*    h      = (float*)alloc((size_t)NN * H * 4);
    float*    r      = (float*)alloc((size_t)NN * H * 4);
    _Float16* rh16   = (_Float16*)alloc((size_t)NN * H * 2);   // fp16 gather shadow
    float*    y1     = (float*)alloc((size_t)NN * H2 * 4);
    float*    part   = (float*)alloc((size_t)NB1 * 2 * 4);
    (void)ws_size; (void)in_sizes; (void)n_in; (void)out_size;

    hipMemsetAsync(counts, 0, (size_t)NN * 2 * 4, stream);

    hist_k<<<(NE + 255) / 256, 256, 0, stream>>>(dst, counts);
    scan_k<<<1, 1024, 0, stream>>>(counts, rowptr);
    scatter_k<<<NE / 256, 256, 0, stream>>>(dst, rowptr, fill, perm);
    packenc_k<<<2500 + NN / 2, 256, 0, stream>>>(perm, src, eattr, srcs, eacsr,
                                                 x, Wn, bn, h, rh16);

    for (int i = 0; i < NL; i++) {
        const float* cin = (i == 0) ? h : r;
        ea_mm1_k<<<NB1, 512, 0, stream>>>(cin, rh16, rowptr, srcs, eacsr, We, be, t, i,
                                          W1 + (size_t)i * H * H2, b1 + i * H2, y1, part);
        int nx = (i == NL - 1) ? 0 : (i + 1);  // next node-LN params (final uses layer 0's)
        mm2_k<<<NB1, 256, 0, stream>>>(y1, g1 + i * H2, bt1 + i * H2,
                                       W2 + (size_t)i * H2 * H, b2 + i * H, part, h,
                                       lng + nx * H, lnb + nx * H, r, rh16, (i == 0) ? 1 : 0);
    }
    mmout_k<<<NBO, 128, 0, stream>>>(r, Wout, bout, out);
}